// Round 24
// baseline (233.902 us; speedup 1.0000x reference)
//
#include <hip/hip_runtime.h>
#include <hip/hip_bf16.h>

typedef __hip_bfloat16 bf16;
#define NEG_BIG (-3.0e38f)

// MFMA fragment types (gfx950: v_mfma_f32_16x16x32_bf16 takes <8 x bfloat>)
typedef __bf16 bf16x8 __attribute__((ext_vector_type(8)));
typedef float  f32x4  __attribute__((ext_vector_type(4)));

// Raw HW exponential: v_exp_f32 computes 2^x. Plain exp2f lowers to the
// precise OCML path (~6 ops + branches) — round-20's regression. One VALU op.
__device__ inline float exp2_hw(float x) {
  float r;
  asm("v_exp_f32 %0, %1" : "=v"(r) : "v"(x));
  return r;
}

__device__ inline void load8_f32(const float* p, float* o) {
  float4 a = *reinterpret_cast<const float4*>(p);
  float4 b = *reinterpret_cast<const float4*>(p + 4);
  o[0]=a.x; o[1]=a.y; o[2]=a.z; o[3]=a.w;
  o[4]=b.x; o[5]=b.y; o[6]=b.z; o[7]=b.w;
}

// k-granule XOR swizzle: element offset of 8-elem granule kg within a row.
__device__ inline int swz8(int row, int kg) { return ((kg ^ ((row >> 3) & 3)) << 3); }

// ---------- Kernel 1: QKV GEMM via MFMA, 256x128 tile, 16 waves, DEPTH-2 prefetch ----------
// (byte-identical to the 182.09us round-23 passer)
__global__ __launch_bounds__(1024)
void qkv_f(const float* __restrict__ X, const float* __restrict__ W,
           const float* __restrict__ bias,
           bf16* __restrict__ q, bf16* __restrict__ k, bf16* __restrict__ v)
{
  // 67584 B: staging As[512][40] (40960) + Bs[256][48] (24576) = 65536,
  // unioned with V-epilogue Vep[128][264] (67584). 2 blocks/CU (135KB<160KB).
  __shared__ __align__(16) unsigned char smem[67584];
  bf16 (*As)[40] = reinterpret_cast<bf16 (*)[40]>(smem);            // [p*256+row]
  bf16 (*Bs)[48] = reinterpret_cast<bf16 (*)[48]>(smem + 40960);    // [p*128+row]

  const int t   = threadIdx.x;
  const int f   = blockIdx.x;               // 0..767
  const int xcd = f & 7, j = f >> 3;        // j 0..95
  const int bm  = xcd * 4 + (j & 3);        // 0..31
  const int bn  = j >> 2;                   // 0..23
  const int gm0 = bm * 256, gn0 = bn * 128;
  const int w    = t >> 6, lane = t & 63;
  const int g    = lane >> 4, l15 = lane & 15;
  const int wr   = w >> 2, wc = w & 3;      // 4x4 wave grid -> wave tile 64x32

  const int am  = t >> 2, akg = t & 3;      // A staging: row am (0..255), granule akg
  const int bnr = t & 127, kg4 = t >> 7;    // B staging: row bnr, 4-elem k-quad kg4 (0..7)

  f32x4 acc[4][2];
#pragma unroll
  for (int i = 0; i < 4; i++)
#pragma unroll
    for (int jj = 0; jj < 2; jj++) acc[i][jj] = {0.f, 0.f, 0.f, 0.f};

  const float* aptr = X + (size_t)(gm0 + am) * 1024 + akg * 8;
  const float* wptr = W + (size_t)(kg4 * 4) * 3072 + gn0 + bnr;

  float a32_0[8], a32_1[8], wb_0[4], wb_1[4];
  load8_f32(aptr, a32_0);                         // slice 0
#pragma unroll
  for (int kk = 0; kk < 4; kk++) wb_0[kk] = wptr[kk * 3072];
  aptr += 32; wptr += 32 * 3072;
  load8_f32(aptr, a32_1);                         // slice 32
#pragma unroll
  for (int kk = 0; kk < 4; kk++) wb_1[kk] = wptr[kk * 3072];

  for (int kt = 0; kt < 1024; kt += 64) {
    // ---- phase 0: consume slice kt (regs set 0, LDS buf 0) ----
    {
      __align__(16) bf16 ab[8];
      __align__(8)  bf16 bb[4];
#pragma unroll
      for (int i = 0; i < 8; i++) ab[i] = __float2bfloat16(a32_0[i]);
#pragma unroll
      for (int i = 0; i < 4; i++) bb[i] = __float2bfloat16(wb_0[i]);
      *reinterpret_cast<uint4*>(&As[am][swz8(am, akg)]) = *reinterpret_cast<const uint4*>(ab);
      *reinterpret_cast<uint2*>(&Bs[bnr][swz8(bnr, kg4 >> 1) + (kg4 & 1) * 4]) =
          *reinterpret_cast<const uint2*>(bb);
      if (kt + 64 < 1024) {          // issue loads for slice kt+64 (2 iters ahead)
        aptr += 32; wptr += 32 * 3072;
        load8_f32(aptr, a32_0);
#pragma unroll
        for (int kk = 0; kk < 4; kk++) wb_0[kk] = wptr[kk * 3072];
      }
      __syncthreads();               // buf0 writes visible
      bf16x8 af[4], bfr[2];
#pragma unroll
      for (int mt = 0; mt < 4; mt++) {
        const int r_ = wr * 64 + mt * 16 + l15;
        af[mt] = *reinterpret_cast<const bf16x8*>(&As[r_][swz8(r_, g)]);
      }
#pragma unroll
      for (int nt = 0; nt < 2; nt++) {
        const int r_ = wc * 32 + nt * 16 + l15;
        bfr[nt] = *reinterpret_cast<const bf16x8*>(&Bs[r_][swz8(r_, g)]);
      }
      __builtin_amdgcn_s_setprio(1);
#pragma unroll
      for (int mt = 0; mt < 4; mt++)
#pragma unroll
        for (int nt = 0; nt < 2; nt++)
          acc[mt][nt] = __builtin_amdgcn_mfma_f32_16x16x32_bf16(af[mt], bfr[nt], acc[mt][nt], 0, 0, 0);
      __builtin_amdgcn_s_setprio(0);
    }
    // ---- phase 1: consume slice kt+32 (regs set 1, LDS buf 1) ----
    {
      __align__(16) bf16 ab[8];
      __align__(8)  bf16 bb[4];
#pragma unroll
      for (int i = 0; i < 8; i++) ab[i] = __float2bfloat16(a32_1[i]);
#pragma unroll
      for (int i = 0; i < 4; i++) bb[i] = __float2bfloat16(wb_1[i]);
      *reinterpret_cast<uint4*>(&As[256 + am][swz8(am, akg)]) = *reinterpret_cast<const uint4*>(ab);
      *reinterpret_cast<uint2*>(&Bs[128 + bnr][swz8(bnr, kg4 >> 1) + (kg4 & 1) * 4]) =
          *reinterpret_cast<const uint2*>(bb);
      if (kt + 96 < 1024) {          // issue loads for slice kt+96
        aptr += 32; wptr += 32 * 3072;
        load8_f32(aptr, a32_1);
#pragma unroll
        for (int kk = 0; kk < 4; kk++) wb_1[kk] = wptr[kk * 3072];
      }
      __syncthreads();               // buf1 writes visible
      bf16x8 af[4], bfr[2];
#pragma unroll
      for (int mt = 0; mt < 4; mt++) {
        const int r_ = wr * 64 + mt * 16 + l15;
        af[mt] = *reinterpret_cast<const bf16x8*>(&As[256 + r_][swz8(r_, g)]);
      }
#pragma unroll
      for (int nt = 0; nt < 2; nt++) {
        const int r_ = wc * 32 + nt * 16 + l15;
        bfr[nt] = *reinterpret_cast<const bf16x8*>(&Bs[128 + r_][swz8(r_, g)]);
      }
      __builtin_amdgcn_s_setprio(1);
#pragma unroll
      for (int mt = 0; mt < 4; mt++)
#pragma unroll
        for (int nt = 0; nt < 2; nt++)
          acc[mt][nt] = __builtin_amdgcn_mfma_f32_16x16x32_bf16(af[mt], bfr[nt], acc[mt][nt], 0, 0, 0);
      __builtin_amdgcn_s_setprio(0);
    }
  }

  // ---- Epilogue. C layout: row s = g*4+r (+16mt+64wr), col c = l15 (+16nt+32wc).
  const int which = gn0 >> 10;                 // block-uniform: 0=Q 1=K 2=V
  if (which == 2) {
    // V (BHDS): transpose through LDS, then coalesced uint4 stores along s.
    bf16 (*Vep)[264] = reinterpret_cast<bf16 (*)[264]>(smem);  // [128 c][256 s +8 pad]
    __syncthreads();                            // staging LDS dead
#pragma unroll
    for (int nt = 0; nt < 2; nt++) {
      const int c = wc * 32 + nt * 16 + l15;
      const float bvs = bias[gn0 + c];
#pragma unroll
      for (int mt = 0; mt < 4; mt++)
#pragma unroll
        for (int r = 0; r < 4; r++) {
          const int s = wr * 64 + mt * 16 + g * 4 + r;
          Vep[c][s] = __float2bfloat16(acc[mt][nt][r] + bvs);
        }
    }
    __syncthreads();
    const int c   = t >> 3, tl = t & 7;         // 8 threads per c-row
    const int bb2 = gm0 >> 11, sl0 = gm0 & 2047;
    const int hh  = ((gn0 - 2048) >> 6) + (c >> 6), d = c & 63;
    bf16* vrow = v + ((size_t)(bb2 * 16 + hh) * 64 + d) * 2048 + sl0;
#pragma unroll
    for (int it = 0; it < 4; it++) {
      const int s_off = tl * 8 + it * 64;
      *reinterpret_cast<uint4*>(vrow + s_off) =
          *reinterpret_cast<const uint4*>(&Vep[c][s_off]);
    }
  } else {
    // Q/K (BHSD): 32B d-chunks per store; adjacent nt chunks merge in TCC.
    bf16* dst = (which == 0) ? q : k;
#pragma unroll
    for (int nt = 0; nt < 2; nt++) {
      const int gc  = gn0 + wc * 32 + nt * 16 + l15;
      const float bvs = bias[gc];
      const int cc = gc & 1023;
      const int hh = cc >> 6, d = cc & 63;
#pragma unroll
      for (int mt = 0; mt < 4; mt++)
#pragma unroll
        for (int r = 0; r < 4; r++) {
          const int gr = gm0 + wr * 64 + mt * 16 + g * 4 + r;
          const int bb2 = gr >> 11, s = gr & 2047;
          float val = acc[mt][nt][r] + bvs;
          if (which == 0) val *= 0.18033688f;   // 0.125 * log2(e): exp2-domain softmax
          dst[((size_t)(bb2 * 16 + hh) * 2048 + s) * 64 + d] = __float2bfloat16(val);
        }
    }
  }
}

// ---------- Kernel 2: causal flash attention, MERGED dual-tile KV sweep ----------
// (round-23 numerics; NEW: SINGLE shared P buffer. P is per-wave private and
// same-wave LDS is in-order, so ordering tile A's PV before tile B's softmax
// lets one 9.2KB Ps serve both tiles. LDS 36.9->27.6KB/block -> 5 blocks/CU
// (138KB), occupancy 16->20 waves/CU (+25% TLP) for this barrier-latency-
// bound kernel. Side effect: PV-A interleaves with softmax-B (MFMA/VALU mix).)
__global__ __launch_bounds__(256, 5)
void attn_f(bf16* __restrict__ qo, const bf16* __restrict__ k, const bf16* __restrict__ v)
{
  __shared__ __align__(16) bf16 Ks[64][72];     // K tile, row = k, col = d
  __shared__ __align__(16) bf16 Vt[64][72];     // V tile, row = d, col = k
  __shared__ __align__(16) bf16 Ps[4][16][72];  // per-wave P (shared A/B, reused)

  const int t    = threadIdx.x;
  const int f    = blockIdx.x;            // 0..1023
  const int xcd  = f & 7;
  const int j    = f >> 3;                // 0..127
  const int a    = j & 7;
  const int qt0  = j >> 3;                // 0..15
  const int hb   = xcd + 8 * a;           // 0..63, fixed per XCD (L2-local heads)
  const int b    = hb >> 4, h = hb & 15;
  const size_t basebh = (size_t)(b * 16 + h) * 2048 * 64;

  const int w    = t >> 6;
  const int lane = t & 63;
  const int g    = lane >> 4;
  const int l15  = lane & 15;

  const int sr = t >> 3;          // staging row 0..31
  const int sc = (t & 7) * 8;     // staging col (elements)
  const bf16* kbase = k + basebh;
  const bf16* vbase = v + basebh;

  const int qtA = 31 - qt0, qtB = qt0;   // qtB < qtA always
  const int qbA = qtA * 64 + w * 16;
  const int qbB = qtB * 64 + w * 16;

  // Q B-fragments for both tiles (operand order in mfma is swapped)
  const bf16* qrowA = qo + basebh + (size_t)(qbA + l15) * 64;
  bf16x8 qfA0 = *reinterpret_cast<const bf16x8*>(qrowA + g * 8);
  bf16x8 qfA1 = *reinterpret_cast<const bf16x8*>(qrowA + 32 + g * 8);
  const bf16* qrowB = qo + basebh + (size_t)(qbB + l15) * 64;
  bf16x8 qfB0 = *reinterpret_cast<const bf16x8*>(qrowB + g * 8);
  bf16x8 qfB1 = *reinterpret_cast<const bf16x8*>(qrowB + 32 + g * 8);

  f32x4 accA[4] = {{0,0,0,0},{0,0,0,0},{0,0,0,0},{0,0,0,0}};
  f32x4 accB[4] = {{0,0,0,0},{0,0,0,0},{0,0,0,0},{0,0,0,0}};
  float mA = NEG_BIG, lA = 0.f, mB = NEG_BIG, lB = 0.f;

  uint4 kreg0, kreg1, vreg0, vreg1;
  {
    kreg0 = *reinterpret_cast<const uint4*>(kbase + (size_t)(sr) * 64 + sc);
    kreg1 = *reinterpret_cast<const uint4*>(kbase + (size_t)(32 + sr) * 64 + sc);
    vreg0 = *reinterpret_cast<const uint4*>(vbase + (size_t)sr * 2048 + sc);
    vreg1 = *reinterpret_cast<const uint4*>(vbase + (size_t)(32 + sr) * 2048 + sc);
  }

#pragma unroll 1
  for (int ct = 0; ct <= qtA; ++ct) {
    const int kv0 = ct * 64;
    const bool doB = (ct <= qtB);         // wave-uniform
    __syncthreads();                      // all waves done reading previous tile
    *reinterpret_cast<uint4*>(&Ks[sr][sc])      = kreg0;
    *reinterpret_cast<uint4*>(&Ks[32 + sr][sc]) = kreg1;
    *reinterpret_cast<uint4*>(&Vt[sr][sc])      = vreg0;
    *reinterpret_cast<uint4*>(&Vt[32 + sr][sc]) = vreg1;
    if (ct < qtA) {                       // prefetch next tile
      const int nv0 = kv0 + 64;
      kreg0 = *reinterpret_cast<const uint4*>(kbase + (size_t)(nv0 + sr) * 64 + sc);
      kreg1 = *reinterpret_cast<const uint4*>(kbase + (size_t)(nv0 + 32 + sr) * 64 + sc);
      vreg0 = *reinterpret_cast<const uint4*>(vbase + (size_t)sr * 2048 + nv0 + sc);
      vreg1 = *reinterpret_cast<const uint4*>(vbase + (size_t)(32 + sr) * 2048 + nv0 + sc);
    }
    __syncthreads();

    // ========== tile A: QK^T -> softmax -> P-write -> PV ==========
    {
      f32x4 st[4];
      __builtin_amdgcn_s_setprio(1);
#pragma unroll
      for (int kt = 0; kt < 4; ++kt) {
        const int kr = kt * 16 + l15;
        bf16x8 kf0 = *reinterpret_cast<const bf16x8*>(&Ks[kr][g * 8]);
        bf16x8 kf1 = *reinterpret_cast<const bf16x8*>(&Ks[kr][32 + g * 8]);
        f32x4 c4 = {0,0,0,0};
        c4 = __builtin_amdgcn_mfma_f32_16x16x32_bf16(kf0, qfA0, c4, 0, 0, 0);
        c4 = __builtin_amdgcn_mfma_f32_16x16x32_bf16(kf1, qfA1, c4, 0, 0, 0);
        st[kt] = c4;
      }
      __builtin_amdgcn_s_setprio(0);
      if (ct == qtA) {
        const int qg = qbA + l15;
#pragma unroll
        for (int kt = 0; kt < 4; ++kt)
#pragma unroll
          for (int r = 0; r < 4; ++r)
            if (kv0 + kt * 16 + g * 4 + r > qg) st[kt][r] = NEG_BIG;
      }
      float m0 = fmaxf(fmaxf(st[0][0], st[0][1]), fmaxf(st[0][2], st[0][3]));
      float m1 = fmaxf(fmaxf(st[1][0], st[1][1]), fmaxf(st[1][2], st[1][3]));
      float m2 = fmaxf(fmaxf(st[2][0], st[2][1]), fmaxf(st[2][2], st[2][3]));
      float m3 = fmaxf(fmaxf(st[3][0], st[3][1]), fmaxf(st[3][2], st[3][3]));
      float mc = fmaxf(fmaxf(m0, m1), fmaxf(m2, m3));
      mc = fmaxf(mc, __shfl_xor(mc, 16));
      mc = fmaxf(mc, __shfl_xor(mc, 32));
      if (!__all(mc - mA <= 11.5413f)) {   // 8 * log2(e)
        const float mn = fmaxf(mA, mc);
        const float alpha = exp2_hw(mA - mn);
        mA = mn;
        lA *= alpha;
#pragma unroll
        for (int r = 0; r < 4; ++r) {
          const float ar = __shfl(alpha, g * 4 + r, 64);
#pragma unroll
          for (int dt = 0; dt < 4; ++dt) accA[dt][r] *= ar;
        }
      }
      float pr[4];
#pragma unroll
      for (int kt = 0; kt < 4; ++kt) {
        float s0 = exp2_hw(st[kt][0] - mA);
        float s1 = exp2_hw(st[kt][1] - mA);
        float s2 = exp2_hw(st[kt][2] - mA);
        float s3 = exp2_hw(st[kt][3] - mA);
        st[kt][0] = s0; st[kt][1] = s1; st[kt][2] = s2; st[kt][3] = s3;
        pr[kt] = (s0 + s1) + (s2 + s3);
      }
      float ps = (pr[0] + pr[1]) + (pr[2] + pr[3]);
      ps += __shfl_xor(ps, 16);
      ps += __shfl_xor(ps, 32);
      lA += ps;
#pragma unroll
      for (int kt = 0; kt < 4; ++kt) {
        union { bf16 hh[4]; uint2 u; } pk;
        pk.hh[0] = __float2bfloat16(st[kt][0]);
        pk.hh[1] = __float2bfloat16(st[kt][1]);
        pk.hh[2] = __float2bfloat16(st[kt][2]);
        pk.hh[3] = __float2bfloat16(st[kt][3]);
        *reinterpret_cast<uint2*>(&Ps[w][l15][kt * 16 + g * 4]) = pk.u;
      }
      __builtin_amdgcn_sched_barrier(0);
      // ---- PV-A (same-wave LDS in-order: Ps[w] writes visible) ----
      __builtin_amdgcn_s_setprio(1);
#pragma unroll
      for (int kc = 0; kc < 2; ++kc) {
        bf16x8 pf = *reinterpret_cast<const bf16x8*>(&Ps[w][l15][kc * 32 + g * 8]);
#pragma unroll
        for (int dt = 0; dt < 4; ++dt) {
          bf16x8 vf = *reinterpret_cast<const bf16x8*>(&Vt[dt * 16 + l15][kc * 32 + g * 8]);
          accA[dt] = __builtin_amdgcn_mfma_f32_16x16x32_bf16(pf, vf, accA[dt], 0, 0, 0);
        }
      }
      __builtin_amdgcn_s_setprio(0);
    }
    // ========== tile B (active while ct <= qtB): QK -> SM -> P -> PV ==========
    if (doB) {
      f32x4 st[4];
      __builtin_amdgcn_s_setprio(1);
#pragma unroll
      for (int kt = 0; kt < 4; ++kt) {
        const int kr = kt * 16 + l15;
        bf16x8 kf0 = *reinterpret_cast<const bf16x8*>(&Ks[kr][g * 8]);
        bf16x8 kf1 = *reinterpret_cast<const bf16x8*>(&Ks[kr][32 + g * 8]);
        f32x4 c4 = {0,0,0,0};
        c4 = __builtin_amdgcn_mfma_f32_16x16x32_bf16(kf0, qfB0, c4, 0, 0, 0);
        c4 = __builtin_amdgcn_mfma_f32_16x16x32_bf16(kf1, qfB1, c4, 0, 0, 0);
        st[kt] = c4;
      }
      __builtin_amdgcn_s_setprio(0);
      if (ct == qtB) {
        const int qg = qbB + l15;
#pragma unroll
        for (int kt = 0; kt < 4; ++kt)
#pragma unroll
          for (int r = 0; r < 4; ++r)
            if (kv0 + kt * 16 + g * 4 + r > qg) st[kt][r] = NEG_BIG;
      }
      float m0 = fmaxf(fmaxf(st[0][0], st[0][1]), fmaxf(st[0][2], st[0][3]));
      float m1 = fmaxf(fmaxf(st[1][0], st[1][1]), fmaxf(st[1][2], st[1][3]));
      float m2 = fmaxf(fmaxf(st[2][0], st[2][1]), fmaxf(st[2][2], st[2][3]));
      float m3 = fmaxf(fmaxf(st[3][0], st[3][1]), fmaxf(st[3][2], st[3][3]));
      float mc = fmaxf(fmaxf(m0, m1), fmaxf(m2, m3));
      mc = fmaxf(mc, __shfl_xor(mc, 16));
      mc = fmaxf(mc, __shfl_xor(mc, 32));
      if (!__all(mc - mB <= 11.5413f)) {   // 8 * log2(e)
        const float mn = fmaxf(mB, mc);
        const float alpha = exp2_hw(mB - mn);
        mB = mn;
        lB *= alpha;
#pragma unroll
        for (int r = 0; r < 4; ++r) {
          const float ar = __shfl(alpha, g * 4 + r, 64);
#pragma unroll
          for (int dt = 0; dt < 4; ++dt) accB[dt][r] *= ar;
        }
      }
      float pr[4];
#pragma unroll
      for (int kt = 0; kt < 4; ++kt) {
        float s0 = exp2_hw(st[kt][0] - mB);
        float s1 = exp2_hw(st[kt][1] - mB);
        float s2 = exp2_hw(st[kt][2] - mB);
        float s3 = exp2_hw(st[kt][3] - mB);
        st[kt][0] = s0; st[kt][1] = s1; st[kt][2] = s2; st[kt][3] = s3;
        pr[kt] = (s0 + s1) + (s2 + s3);
      }
      float ps = (pr[0] + pr[1]) + (pr[2] + pr[3]);
      ps += __shfl_xor(ps, 16);
      ps += __shfl_xor(ps, 32);
      lB += ps;
#pragma unroll
      for (int kt = 0; kt < 4; ++kt) {
        union { bf16 hh[4]; uint2 u; } pk;
        pk.hh[0] = __float2bfloat16(st[kt][0]);
        pk.hh[1] = __float2bfloat16(st[kt][1]);
        pk.hh[2] = __float2bfloat16(st[kt][2]);
        pk.hh[3] = __float2bfloat16(st[kt][3]);
        *reinterpret_cast<uint2*>(&Ps[w][l15][kt * 16 + g * 4]) = pk.u;
      }
      __builtin_amdgcn_sched_barrier(0);
      // ---- PV-B ----
      __builtin_amdgcn_s_setprio(1);
#pragma unroll
      for (int kc = 0; kc < 2; ++kc) {
        bf16x8 pf = *reinterpret_cast<const bf16x8*>(&Ps[w][l15][kc * 32 + g * 8]);
#pragma unroll
        for (int dt = 0; dt < 4; ++dt) {
          bf16x8 vf = *reinterpret_cast<const bf16x8*>(&Vt[dt * 16 + l15][kc * 32 + g * 8]);
          accB[dt] = __builtin_amdgcn_mfma_f32_16x16x32_bf16(pf, vf, accB[dt], 0, 0, 0);
        }
      }
      __builtin_amdgcn_s_setprio(0);
    }
  }

  // ---- epilogues: O = acc / l, in-place over each tile's Q slab ----
  bf16* op = qo + basebh;
  {
    const float linv = 1.f / lA;
    float inv[4];
#pragma unroll
    for (int r = 0; r < 4; ++r) inv[r] = __shfl(linv, g * 4 + r, 64);
#pragma unroll
    for (int dt = 0; dt < 4; ++dt)
#pragma unroll
      for (int r = 0; r < 4; ++r)
        op[(size_t)(qbA + g * 4 + r) * 64 + dt * 16 + l15] =
            __float2bfloat16(accA[dt][r] * inv[r]);
  }
  {
    const float linv = 1.f / lB;
    float inv[4];
#pragma unroll
    for (int r = 0; r < 4; ++r) inv[r] = __shfl(linv, g * 4 + r, 64);
#pragma unroll
    for (int dt = 0; dt < 4; ++dt)
#pragma unroll
      for (int r = 0; r < 4; ++r)
        op[(size_t)(qbB + g * 4 + r) * 64 + dt * 16 + l15] =
            __float2bfloat16(accB[dt][r] * inv[r]);
  }
}

// ---------- Kernel 3: projection via MFMA, 256x128 tile, 16 waves, DEPTH-2 prefetch ----------
// (byte-identical to the 182.09us round-23 passer)
__global__ __launch_bounds__(1024)
void proj_f(const bf16* __restrict__ A, const float* __restrict__ W,
            const float* __restrict__ bias, float* __restrict__ out)
{
  __shared__ __align__(16) bf16 As[2][256][40];
  __shared__ __align__(16) bf16 Bs[2][128][48];
  const int t   = threadIdx.x;
  const int f   = blockIdx.x;               // 0..255
  const int xcd = f & 7, j = f >> 3;        // j 0..31
  const int bm  = xcd * 4 + (j & 3);        // 0..31
  const int bn  = j >> 2;                   // 0..7
  const int gm0 = bm * 256, gn0 = bn * 128;
  const int w    = t >> 6, lane = t & 63;
  const int g    = lane >> 4, l15 = lane & 15;
  const int wr   = w >> 2, wc = w & 3;      // 4x4 wave grid -> wave tile 64x32

  const int am  = t >> 2, akg = t & 3;
  const int bnr = t & 127, kg4 = t >> 7;

  const int gr_l = gm0 + am;
  const int bb_l = gr_l >> 11, s_l = gr_l & 2047;
  const bf16* abase = A + (size_t)bb_l * 2097152 + (size_t)s_l * 64;

  f32x4 acc[4][2];
#pragma unroll
  for (int i = 0; i < 4; i++)
#pragma unroll
    for (int jj = 0; jj < 2; jj++) acc[i][jj] = {0.f, 0.f, 0.f, 0.f};

  const float* wptr = W + (size_t)(kg4 * 4) * 1024 + gn0 + bnr;

  uint4 a0_0, a0_1;
  float wb_0[4], wb_1[4];
  {
    const int c0 = akg * 8;                 // slice 0
    a0_0 = *reinterpret_cast<const uint4*>(abase + (size_t)(c0 >> 6) * 131072 + (c0 & 63));
    const int c1 = 32 + akg * 8;            // slice 32
    a0_1 = *reinterpret_cast<const uint4*>(abase + (size_t)(c1 >> 6) * 131072 + (c1 & 63));
  }
#pragma unroll
  for (int kk = 0; kk < 4; kk++) wb_0[kk] = wptr[kk * 1024];
  wptr += 32 * 1024;
#pragma unroll
  for (int kk = 0; kk < 4; kk++) wb_1[kk] = wptr[kk * 1024];

  for (int kt = 0; kt < 1024; kt += 64) {
    // ---- phase 0: consume slice kt ----
    {
      __align__(8) bf16 bb[4];
#pragma unroll
      for (int i = 0; i < 4; i++) bb[i] = __float2bfloat16(wb_0[i]);
      *reinterpret_cast<uint4*>(&As[0][am][swz8(am, akg)]) = a0_0;
      *reinterpret_cast<uint2*>(&Bs[0][bnr][swz8(bnr, kg4 >> 1) + (kg4 & 1) * 4]) =
          *reinterpret_cast<const uint2*>(bb);
      if (kt + 64 < 1024) {          // issue loads for slice kt+64
        const int c0 = kt + 64 + akg * 8;
        a0_0 = *reinterpret_cast<const uint4*>(abase + (size_t)(c0 >> 6) * 131072 + (c0 & 63));
        wptr += 32 * 1024;
#pragma unroll
        for (int kk = 0; kk < 4; kk++) wb_0[kk] = wptr[kk * 1024];
      }
      __syncthreads();
      bf16x8 af[4], bfr[2];
#pragma unroll
      for (int mt = 0; mt < 4; mt++) {
        const int r_ = wr * 64 + mt * 16 + l15;
        af[mt] = *reinterpret_cast<const bf16x8*>(&As[0][r_][swz8(r_, g)]);
      }
#pragma unroll
      for (int nt = 0; nt < 2; nt++) {
        const int r_ = wc * 32 + nt * 16 + l15;
        bfr[nt] = *reinterpret_cast<const bf16x8*>(&Bs[0][r_][swz8(r_, g)]);
      }
      __builtin_amdgcn_s_setprio(1);
#pragma unroll
      for (int mt = 0; mt < 4; mt++)
#pragma unroll
        for (int nt = 0; nt < 2; nt++)
          acc[mt][nt] = __builtin_amdgcn_mfma_f32_16x16x32_bf16(af[mt], bfr[nt], acc[mt][nt], 0, 0, 0);
      __builtin_amdgcn_s_setprio(0);
    }
    // ---- phase 1: consume slice kt+32 ----
    {
      __align__(8) bf16 bb[4];
#pragma unroll
      for (int i = 0; i < 4; i++) bb[i] = __float2bfloat16(wb_1[i]);
      *reinterpret_cast<uint4*>(&As[1][am][swz8(am, akg)]) = a0_1;
      *reinterpret_cast<uint2*>(&Bs[1][bnr][swz8(bnr, kg4 >> 1) + (kg4 & 1) * 4]) =
          *reinterpret_cast<const uint2*>(bb);
      if (kt + 96 < 1024) {          // issue loads for slice kt+96
        const int c1 = kt + 96 + akg * 8;
        a0_1 = *reinterpret_cast<const uint4*>(abase + (size_t)(c1 >> 6) * 131072 + (c1 & 63));
        wptr += 32 * 1024;
#pragma unroll
        for (int kk = 0; kk < 4; kk++) wb_1[kk] = wptr[kk * 1024];
      }
      __syncthreads();
      bf16x8 af[4], bfr[2];
#pragma unroll
      for (int mt = 0; mt < 4; mt++) {
        const int r_ = wr * 64 + mt * 16 + l15;
        af[mt] = *reinterpret_cast<const bf16x8*>(&As[1][r_][swz8(r_, g)]);
      }
#pragma unroll
      for (int nt = 0; nt < 2; nt++) {
        const int r_ = wc * 32 + nt * 16 + l15;
        bfr[nt] = *reinterpret_cast<const bf16x8*>(&Bs[1][r_][swz8(r_, g)]);
      }
      __builtin_amdgcn_s_setprio(1);
#pragma unroll
      for (int mt = 0; mt < 4; mt++)
#pragma unroll
        for (int nt = 0; nt < 2; nt++)
          acc[mt][nt] = __builtin_amdgcn_mfma_f32_16x16x32_bf16(af[mt], bfr[nt], acc[mt][nt], 0, 0, 0);
      __builtin_amdgcn_s_setprio(0);
    }
  }

#pragma unroll
  for (int nt = 0; nt < 2; nt++) {
    const int gc = gn0 + wc * 32 + nt * 16 + l15;
    const float bvs = bias[gc];
#pragma unroll
    for (int mt = 0; mt < 4; mt++)
#pragma unroll
      for (int r = 0; r < 4; r++) {
        const int gr = gm0 + wr * 64 + mt * 16 + g * 4 + r;
        out[(size_t)gr * 1024 + gc] = acc[mt][nt][r] + bvs;
      }
  }
}

extern "C" void kernel_launch(void* const* d_in, const int* in_sizes, int n_in,
                              void* d_out, int out_size, void* d_ws, size_t ws_size,
                              hipStream_t stream)
{
  const float *x = nullptr, *W_attn = nullptr, *b_attn = nullptr,
              *W_proj = nullptr, *b_proj = nullptr;
  for (int i = 0; i < n_in; i++) {
    switch (in_sizes[i]) {
      case 8388608: x      = (const float*)d_in[i]; break;  // [4,2048,1024]
      case 3145728: W_attn = (const float*)d_in[i]; break;  // [1024,3072]
      case 3072:    b_attn = (const float*)d_in[i]; break;
      case 1048576: W_proj = (const float*)d_in[i]; break;  // [1024,1024]
      case 1024:    b_proj = (const float*)d_in[i]; break;
      default: break;
    }
  }
  if (!x || !W_attn || !b_attn || !W_proj || !b_proj) {
    x = (const float*)d_in[0]; W_attn = (const float*)d_in[1];
    b_attn = (const float*)d_in[2]; W_proj = (const float*)d_in[3];
    b_proj = (const float*)d_in[4];
  }
  float* out = (float*)d_out;        // 8388608 f32 = 32 MiB

  // Memory plan (inputs never written; ws requirement 16 MiB):
  //   Q -> ws[0:16M)  bf16 BHSD, pre-scaled by 0.125*log2e (overwritten by O)
  //   K -> d_out bytes [0:16M)  bf16 BHSD   } dead before proj's f32 writes
  //   V -> d_out bytes [16M:32M) bf16 BHDS  }  (transposed for MFMA PV)
  const size_t NE = 8388608;         // bf16 elements per 16 MiB tensor
  bf16* qb = (bf16*)d_ws;
  bf16* kb = (bf16*)d_out;
  bf16* vb = kb + NE;

  qkv_f <<<dim3(768), 1024, 0, stream>>>(x, W_attn, b_attn, qb, kb, vb);
  attn_f<<<dim3(1024), 256, 0, stream>>>(qb, kb, vb);
  proj_f<<<dim3(256), 1024, 0, stream>>>(qb, W_proj, b_proj, out);
}

// Round 25
// 181.611 us; speedup vs baseline: 1.2879x; 1.2879x over previous
//
#include <hip/hip_runtime.h>
#include <hip/hip_bf16.h>

typedef __hip_bfloat16 bf16;
#define NEG_BIG (-3.0e38f)

// MFMA fragment types (gfx950: v_mfma_f32_16x16x32_bf16 takes <8 x bfloat>)
typedef __bf16 bf16x8 __attribute__((ext_vector_type(8)));
typedef float  f32x4  __attribute__((ext_vector_type(4)));

// Raw HW exponential: v_exp_f32 computes 2^x. Plain exp2f lowers to the
// precise OCML path (~6 ops + branches) — round-20's regression. One VALU op.
__device__ inline float exp2_hw(float x) {
  float r;
  asm("v_exp_f32 %0, %1" : "=v"(r) : "v"(x));
  return r;
}

__device__ inline void load8_f32(const float* p, float* o) {
  float4 a = *reinterpret_cast<const float4*>(p);
  float4 b = *reinterpret_cast<const float4*>(p + 4);
  o[0]=a.x; o[1]=a.y; o[2]=a.z; o[3]=a.w;
  o[4]=b.x; o[5]=b.y; o[6]=b.z; o[7]=b.w;
}

// k-granule XOR swizzle: element offset of 8-elem granule kg within a row.
__device__ inline int swz8(int row, int kg) { return ((kg ^ ((row >> 3) & 3)) << 3); }

// ---------- Kernel 1: QKV GEMM via MFMA, 256x128 tile, 16 waves, DEPTH-2 prefetch ----------
// (Q pre-scale folds log2(e): 0.125 * 1.4426950 = 0.18033688 -> exp2-domain softmax)
__global__ __launch_bounds__(1024)
void qkv_f(const float* __restrict__ X, const float* __restrict__ W,
           const float* __restrict__ bias,
           bf16* __restrict__ q, bf16* __restrict__ k, bf16* __restrict__ v)
{
  // 67584 B: staging As[512][40] (40960) + Bs[256][48] (24576) = 65536,
  // unioned with V-epilogue Vep[128][264] (67584). 2 blocks/CU (135KB<160KB).
  __shared__ __align__(16) unsigned char smem[67584];
  bf16 (*As)[40] = reinterpret_cast<bf16 (*)[40]>(smem);            // [p*256+row]
  bf16 (*Bs)[48] = reinterpret_cast<bf16 (*)[48]>(smem + 40960);    // [p*128+row]

  const int t   = threadIdx.x;
  const int f   = blockIdx.x;               // 0..767
  const int xcd = f & 7, j = f >> 3;        // j 0..95
  const int bm  = xcd * 4 + (j & 3);        // 0..31
  const int bn  = j >> 2;                   // 0..23
  const int gm0 = bm * 256, gn0 = bn * 128;
  const int w    = t >> 6, lane = t & 63;
  const int g    = lane >> 4, l15 = lane & 15;
  const int wr   = w >> 2, wc = w & 3;      // 4x4 wave grid -> wave tile 64x32

  const int am  = t >> 2, akg = t & 3;      // A staging: row am (0..255), granule akg
  const int bnr = t & 127, kg4 = t >> 7;    // B staging: row bnr, 4-elem k-quad kg4 (0..7)

  f32x4 acc[4][2];
#pragma unroll
  for (int i = 0; i < 4; i++)
#pragma unroll
    for (int jj = 0; jj < 2; jj++) acc[i][jj] = {0.f, 0.f, 0.f, 0.f};

  const float* aptr = X + (size_t)(gm0 + am) * 1024 + akg * 8;
  const float* wptr = W + (size_t)(kg4 * 4) * 3072 + gn0 + bnr;

  float a32_0[8], a32_1[8], wb_0[4], wb_1[4];
  load8_f32(aptr, a32_0);                         // slice 0
#pragma unroll
  for (int kk = 0; kk < 4; kk++) wb_0[kk] = wptr[kk * 3072];
  aptr += 32; wptr += 32 * 3072;
  load8_f32(aptr, a32_1);                         // slice 32
#pragma unroll
  for (int kk = 0; kk < 4; kk++) wb_1[kk] = wptr[kk * 3072];

  for (int kt = 0; kt < 1024; kt += 64) {
    // ---- phase 0: consume slice kt (regs set 0, LDS buf 0) ----
    {
      __align__(16) bf16 ab[8];
      __align__(8)  bf16 bb[4];
#pragma unroll
      for (int i = 0; i < 8; i++) ab[i] = __float2bfloat16(a32_0[i]);
#pragma unroll
      for (int i = 0; i < 4; i++) bb[i] = __float2bfloat16(wb_0[i]);
      *reinterpret_cast<uint4*>(&As[am][swz8(am, akg)]) = *reinterpret_cast<const uint4*>(ab);
      *reinterpret_cast<uint2*>(&Bs[bnr][swz8(bnr, kg4 >> 1) + (kg4 & 1) * 4]) =
          *reinterpret_cast<const uint2*>(bb);
      if (kt + 64 < 1024) {          // issue loads for slice kt+64 (2 iters ahead)
        aptr += 32; wptr += 32 * 3072;
        load8_f32(aptr, a32_0);
#pragma unroll
        for (int kk = 0; kk < 4; kk++) wb_0[kk] = wptr[kk * 3072];
      }
      __syncthreads();               // buf0 writes visible
      bf16x8 af[4], bfr[2];
#pragma unroll
      for (int mt = 0; mt < 4; mt++) {
        const int r_ = wr * 64 + mt * 16 + l15;
        af[mt] = *reinterpret_cast<const bf16x8*>(&As[r_][swz8(r_, g)]);
      }
#pragma unroll
      for (int nt = 0; nt < 2; nt++) {
        const int r_ = wc * 32 + nt * 16 + l15;
        bfr[nt] = *reinterpret_cast<const bf16x8*>(&Bs[r_][swz8(r_, g)]);
      }
      __builtin_amdgcn_s_setprio(1);
#pragma unroll
      for (int mt = 0; mt < 4; mt++)
#pragma unroll
        for (int nt = 0; nt < 2; nt++)
          acc[mt][nt] = __builtin_amdgcn_mfma_f32_16x16x32_bf16(af[mt], bfr[nt], acc[mt][nt], 0, 0, 0);
      __builtin_amdgcn_s_setprio(0);
    }
    // ---- phase 1: consume slice kt+32 (regs set 1, LDS buf 1) ----
    {
      __align__(16) bf16 ab[8];
      __align__(8)  bf16 bb[4];
#pragma unroll
      for (int i = 0; i < 8; i++) ab[i] = __float2bfloat16(a32_1[i]);
#pragma unroll
      for (int i = 0; i < 4; i++) bb[i] = __float2bfloat16(wb_1[i]);
      *reinterpret_cast<uint4*>(&As[256 + am][swz8(am, akg)]) = *reinterpret_cast<const uint4*>(ab);
      *reinterpret_cast<uint2*>(&Bs[128 + bnr][swz8(bnr, kg4 >> 1) + (kg4 & 1) * 4]) =
          *reinterpret_cast<const uint2*>(bb);
      if (kt + 96 < 1024) {          // issue loads for slice kt+96
        aptr += 32; wptr += 32 * 3072;
        load8_f32(aptr, a32_1);
#pragma unroll
        for (int kk = 0; kk < 4; kk++) wb_1[kk] = wptr[kk * 3072];
      }
      __syncthreads();               // buf1 writes visible
      bf16x8 af[4], bfr[2];
#pragma unroll
      for (int mt = 0; mt < 4; mt++) {
        const int r_ = wr * 64 + mt * 16 + l15;
        af[mt] = *reinterpret_cast<const bf16x8*>(&As[256 + r_][swz8(r_, g)]);
      }
#pragma unroll
      for (int nt = 0; nt < 2; nt++) {
        const int r_ = wc * 32 + nt * 16 + l15;
        bfr[nt] = *reinterpret_cast<const bf16x8*>(&Bs[128 + r_][swz8(r_, g)]);
      }
      __builtin_amdgcn_s_setprio(1);
#pragma unroll
      for (int mt = 0; mt < 4; mt++)
#pragma unroll
        for (int nt = 0; nt < 2; nt++)
          acc[mt][nt] = __builtin_amdgcn_mfma_f32_16x16x32_bf16(af[mt], bfr[nt], acc[mt][nt], 0, 0, 0);
      __builtin_amdgcn_s_setprio(0);
    }
  }

  // ---- Epilogue. C layout: row s = g*4+r (+16mt+64wr), col c = l15 (+16nt+32wc).
  const int which = gn0 >> 10;                 // block-uniform: 0=Q 1=K 2=V
  if (which == 2) {
    // V (BHDS): transpose through LDS, then coalesced uint4 stores along s.
    bf16 (*Vep)[264] = reinterpret_cast<bf16 (*)[264]>(smem);  // [128 c][256 s +8 pad]
    __syncthreads();                            // staging LDS dead
#pragma unroll
    for (int nt = 0; nt < 2; nt++) {
      const int c = wc * 32 + nt * 16 + l15;
      const float bvs = bias[gn0 + c];
#pragma unroll
      for (int mt = 0; mt < 4; mt++)
#pragma unroll
        for (int r = 0; r < 4; r++) {
          const int s = wr * 64 + mt * 16 + g * 4 + r;
          Vep[c][s] = __float2bfloat16(acc[mt][nt][r] + bvs);
        }
    }
    __syncthreads();
    const int c   = t >> 3, tl = t & 7;         // 8 threads per c-row
    const int bb2 = gm0 >> 11, sl0 = gm0 & 2047;
    const int hh  = ((gn0 - 2048) >> 6) + (c >> 6), d = c & 63;
    bf16* vrow = v + ((size_t)(bb2 * 16 + hh) * 64 + d) * 2048 + sl0;
#pragma unroll
    for (int it = 0; it < 4; it++) {
      const int s_off = tl * 8 + it * 64;
      *reinterpret_cast<uint4*>(vrow + s_off) =
          *reinterpret_cast<const uint4*>(&Vep[c][s_off]);
    }
  } else {
    // Q/K (BHSD): 32B d-chunks per store; adjacent nt chunks merge in TCC.
    bf16* dst = (which == 0) ? q : k;
#pragma unroll
    for (int nt = 0; nt < 2; nt++) {
      const int gc  = gn0 + wc * 32 + nt * 16 + l15;
      const float bvs = bias[gc];
      const int cc = gc & 1023;
      const int hh = cc >> 6, d = cc & 63;
#pragma unroll
      for (int mt = 0; mt < 4; mt++)
#pragma unroll
        for (int r = 0; r < 4; r++) {
          const int gr = gm0 + wr * 64 + mt * 16 + g * 4 + r;
          const int bb2 = gr >> 11, s = gr & 2047;
          float val = acc[mt][nt][r] + bvs;
          if (which == 0) val *= 0.18033688f;   // 0.125 * log2(e): exp2-domain softmax
          dst[((size_t)(bb2 * 16 + hh) * 2048 + s) * 64 + d] = __float2bfloat16(val);
        }
    }
  }
}

// ---------- Kernel 2: causal flash attention, MERGED dual-tile KV sweep ----------
// (round-23 structure restored byte-for-byte: dual P buffers, 4 blocks/CU.
// Round-24's single-P + launch_bounds(256,5) capped VGPR at 102 and spilled
// the dual-accumulator state (~260MB scratch traffic). This config is the
// verified session optimum: 182.09us.)
__global__ __launch_bounds__(256, 4)
void attn_f(bf16* __restrict__ qo, const bf16* __restrict__ k, const bf16* __restrict__ v)
{
  __shared__ __align__(16) bf16 Ks[64][72];        // K tile, row = k, col = d
  __shared__ __align__(16) bf16 Vt[64][72];        // V tile, row = d, col = k
  __shared__ __align__(16) bf16 Ps[2][4][16][72];  // per-tile, per-wave P

  const int t    = threadIdx.x;
  const int f    = blockIdx.x;            // 0..1023
  const int xcd  = f & 7;
  const int j    = f >> 3;                // 0..127
  const int a    = j & 7;
  const int qt0  = j >> 3;                // 0..15
  const int hb   = xcd + 8 * a;           // 0..63, fixed per XCD (L2-local heads)
  const int b    = hb >> 4, h = hb & 15;
  const size_t basebh = (size_t)(b * 16 + h) * 2048 * 64;

  const int w    = t >> 6;
  const int lane = t & 63;
  const int g    = lane >> 4;
  const int l15  = lane & 15;

  const int sr = t >> 3;          // staging row 0..31
  const int sc = (t & 7) * 8;     // staging col (elements)
  const bf16* kbase = k + basebh;
  const bf16* vbase = v + basebh;

  const int qtA = 31 - qt0, qtB = qt0;   // qtB < qtA always
  const int qbA = qtA * 64 + w * 16;
  const int qbB = qtB * 64 + w * 16;

  // Q B-fragments for both tiles (operand order in mfma is swapped)
  const bf16* qrowA = qo + basebh + (size_t)(qbA + l15) * 64;
  bf16x8 qfA0 = *reinterpret_cast<const bf16x8*>(qrowA + g * 8);
  bf16x8 qfA1 = *reinterpret_cast<const bf16x8*>(qrowA + 32 + g * 8);
  const bf16* qrowB = qo + basebh + (size_t)(qbB + l15) * 64;
  bf16x8 qfB0 = *reinterpret_cast<const bf16x8*>(qrowB + g * 8);
  bf16x8 qfB1 = *reinterpret_cast<const bf16x8*>(qrowB + 32 + g * 8);

  f32x4 accA[4] = {{0,0,0,0},{0,0,0,0},{0,0,0,0},{0,0,0,0}};
  f32x4 accB[4] = {{0,0,0,0},{0,0,0,0},{0,0,0,0},{0,0,0,0}};
  float mA = NEG_BIG, lA = 0.f, mB = NEG_BIG, lB = 0.f;

  uint4 kreg0, kreg1, vreg0, vreg1;
  {
    kreg0 = *reinterpret_cast<const uint4*>(kbase + (size_t)(sr) * 64 + sc);
    kreg1 = *reinterpret_cast<const uint4*>(kbase + (size_t)(32 + sr) * 64 + sc);
    vreg0 = *reinterpret_cast<const uint4*>(vbase + (size_t)sr * 2048 + sc);
    vreg1 = *reinterpret_cast<const uint4*>(vbase + (size_t)(32 + sr) * 2048 + sc);
  }

#pragma unroll 1
  for (int ct = 0; ct <= qtA; ++ct) {
    const int kv0 = ct * 64;
    const bool doB = (ct <= qtB);         // wave-uniform
    __syncthreads();                      // all waves done reading previous tile
    *reinterpret_cast<uint4*>(&Ks[sr][sc])      = kreg0;
    *reinterpret_cast<uint4*>(&Ks[32 + sr][sc]) = kreg1;
    *reinterpret_cast<uint4*>(&Vt[sr][sc])      = vreg0;
    *reinterpret_cast<uint4*>(&Vt[32 + sr][sc]) = vreg1;
    if (ct < qtA) {                       // prefetch next tile
      const int nv0 = kv0 + 64;
      kreg0 = *reinterpret_cast<const uint4*>(kbase + (size_t)(nv0 + sr) * 64 + sc);
      kreg1 = *reinterpret_cast<const uint4*>(kbase + (size_t)(nv0 + 32 + sr) * 64 + sc);
      vreg0 = *reinterpret_cast<const uint4*>(vbase + (size_t)sr * 2048 + nv0 + sc);
      vreg1 = *reinterpret_cast<const uint4*>(vbase + (size_t)(32 + sr) * 2048 + nv0 + sc);
    }
    __syncthreads();

    // ================= tile A: QK^T, softmax, P-write =================
    {
      f32x4 st[4];
      __builtin_amdgcn_s_setprio(1);
#pragma unroll
      for (int kt = 0; kt < 4; ++kt) {
        const int kr = kt * 16 + l15;
        bf16x8 kf0 = *reinterpret_cast<const bf16x8*>(&Ks[kr][g * 8]);
        bf16x8 kf1 = *reinterpret_cast<const bf16x8*>(&Ks[kr][32 + g * 8]);
        f32x4 c4 = {0,0,0,0};
        c4 = __builtin_amdgcn_mfma_f32_16x16x32_bf16(kf0, qfA0, c4, 0, 0, 0);
        c4 = __builtin_amdgcn_mfma_f32_16x16x32_bf16(kf1, qfA1, c4, 0, 0, 0);
        st[kt] = c4;
      }
      __builtin_amdgcn_s_setprio(0);
      if (ct == qtA) {
        const int qg = qbA + l15;
#pragma unroll
        for (int kt = 0; kt < 4; ++kt)
#pragma unroll
          for (int r = 0; r < 4; ++r)
            if (kv0 + kt * 16 + g * 4 + r > qg) st[kt][r] = NEG_BIG;
      }
      float m0 = fmaxf(fmaxf(st[0][0], st[0][1]), fmaxf(st[0][2], st[0][3]));
      float m1 = fmaxf(fmaxf(st[1][0], st[1][1]), fmaxf(st[1][2], st[1][3]));
      float m2 = fmaxf(fmaxf(st[2][0], st[2][1]), fmaxf(st[2][2], st[2][3]));
      float m3 = fmaxf(fmaxf(st[3][0], st[3][1]), fmaxf(st[3][2], st[3][3]));
      float mc = fmaxf(fmaxf(m0, m1), fmaxf(m2, m3));
      mc = fmaxf(mc, __shfl_xor(mc, 16));
      mc = fmaxf(mc, __shfl_xor(mc, 32));
      if (!__all(mc - mA <= 11.5413f)) {   // 8 * log2(e)
        const float mn = fmaxf(mA, mc);
        const float alpha = exp2_hw(mA - mn);
        mA = mn;
        lA *= alpha;
#pragma unroll
        for (int r = 0; r < 4; ++r) {
          const float ar = __shfl(alpha, g * 4 + r, 64);
#pragma unroll
          for (int dt = 0; dt < 4; ++dt) accA[dt][r] *= ar;
        }
      }
      float pr[4];
#pragma unroll
      for (int kt = 0; kt < 4; ++kt) {
        float s0 = exp2_hw(st[kt][0] - mA);
        float s1 = exp2_hw(st[kt][1] - mA);
        float s2 = exp2_hw(st[kt][2] - mA);
        float s3 = exp2_hw(st[kt][3] - mA);
        st[kt][0] = s0; st[kt][1] = s1; st[kt][2] = s2; st[kt][3] = s3;
        pr[kt] = (s0 + s1) + (s2 + s3);
      }
      float ps = (pr[0] + pr[1]) + (pr[2] + pr[3]);
      ps += __shfl_xor(ps, 16);
      ps += __shfl_xor(ps, 32);
      lA += ps;
#pragma unroll
      for (int kt = 0; kt < 4; ++kt) {
        union { bf16 hh[4]; uint2 u; } pk;
        pk.hh[0] = __float2bfloat16(st[kt][0]);
        pk.hh[1] = __float2bfloat16(st[kt][1]);
        pk.hh[2] = __float2bfloat16(st[kt][2]);
        pk.hh[3] = __float2bfloat16(st[kt][3]);
        *reinterpret_cast<uint2*>(&Ps[0][w][l15][kt * 16 + g * 4]) = pk.u;
      }
    }
    // ================= tile B (active while ct <= qtB) =================
    if (doB) {
      f32x4 st[4];
      __builtin_amdgcn_s_setprio(1);
#pragma unroll
      for (int kt = 0; kt < 4; ++kt) {
        const int kr = kt * 16 + l15;
        bf16x8 kf0 = *reinterpret_cast<const bf16x8*>(&Ks[kr][g * 8]);
        bf16x8 kf1 = *reinterpret_cast<const bf16x8*>(&Ks[kr][32 + g * 8]);
        f32x4 c4 = {0,0,0,0};
        c4 = __builtin_amdgcn_mfma_f32_16x16x32_bf16(kf0, qfB0, c4, 0, 0, 0);
        c4 = __builtin_amdgcn_mfma_f32_16x16x32_bf16(kf1, qfB1, c4, 0, 0, 0);
        st[kt] = c4;
      }
      __builtin_amdgcn_s_setprio(0);
      if (ct == qtB) {
        const int qg = qbB + l15;
#pragma unroll
        for (int kt = 0; kt < 4; ++kt)
#pragma unroll
          for (int r = 0; r < 4; ++r)
            if (kv0 + kt * 16 + g * 4 + r > qg) st[kt][r] = NEG_BIG;
      }
      float m0 = fmaxf(fmaxf(st[0][0], st[0][1]), fmaxf(st[0][2], st[0][3]));
      float m1 = fmaxf(fmaxf(st[1][0], st[1][1]), fmaxf(st[1][2], st[1][3]));
      float m2 = fmaxf(fmaxf(st[2][0], st[2][1]), fmaxf(st[2][2], st[2][3]));
      float m3 = fmaxf(fmaxf(st[3][0], st[3][1]), fmaxf(st[3][2], st[3][3]));
      float mc = fmaxf(fmaxf(m0, m1), fmaxf(m2, m3));
      mc = fmaxf(mc, __shfl_xor(mc, 16));
      mc = fmaxf(mc, __shfl_xor(mc, 32));
      if (!__all(mc - mB <= 11.5413f)) {   // 8 * log2(e)
        const float mn = fmaxf(mB, mc);
        const float alpha = exp2_hw(mB - mn);
        mB = mn;
        lB *= alpha;
#pragma unroll
        for (int r = 0; r < 4; ++r) {
          const float ar = __shfl(alpha, g * 4 + r, 64);
#pragma unroll
          for (int dt = 0; dt < 4; ++dt) accB[dt][r] *= ar;
        }
      }
      float pr[4];
#pragma unroll
      for (int kt = 0; kt < 4; ++kt) {
        float s0 = exp2_hw(st[kt][0] - mB);
        float s1 = exp2_hw(st[kt][1] - mB);
        float s2 = exp2_hw(st[kt][2] - mB);
        float s3 = exp2_hw(st[kt][3] - mB);
        st[kt][0] = s0; st[kt][1] = s1; st[kt][2] = s2; st[kt][3] = s3;
        pr[kt] = (s0 + s1) + (s2 + s3);
      }
      float ps = (pr[0] + pr[1]) + (pr[2] + pr[3]);
      ps += __shfl_xor(ps, 16);
      ps += __shfl_xor(ps, 32);
      lB += ps;
#pragma unroll
      for (int kt = 0; kt < 4; ++kt) {
        union { bf16 hh[4]; uint2 u; } pk;
        pk.hh[0] = __float2bfloat16(st[kt][0]);
        pk.hh[1] = __float2bfloat16(st[kt][1]);
        pk.hh[2] = __float2bfloat16(st[kt][2]);
        pk.hh[3] = __float2bfloat16(st[kt][3]);
        *reinterpret_cast<uint2*>(&Ps[1][w][l15][kt * 16 + g * 4]) = pk.u;
      }
    }
    __builtin_amdgcn_sched_barrier(0);

    // ================= PV for both tiles =================
    __builtin_amdgcn_s_setprio(1);
#pragma unroll
    for (int kc = 0; kc < 2; ++kc) {
      bf16x8 pf = *reinterpret_cast<const bf16x8*>(&Ps[0][w][l15][kc * 32 + g * 8]);
#pragma unroll
      for (int dt = 0; dt < 4; ++dt) {
        bf16x8 vf = *reinterpret_cast<const bf16x8*>(&Vt[dt * 16 + l15][kc * 32 + g * 8]);
        accA[dt] = __builtin_amdgcn_mfma_f32_16x16x32_bf16(pf, vf, accA[dt], 0, 0, 0);
      }
    }
    if (doB) {
#pragma unroll
      for (int kc = 0; kc < 2; ++kc) {
        bf16x8 pf = *reinterpret_cast<const bf16x8*>(&Ps[1][w][l15][kc * 32 + g * 8]);
#pragma unroll
        for (int dt = 0; dt < 4; ++dt) {
          bf16x8 vf = *reinterpret_cast<const bf16x8*>(&Vt[dt * 16 + l15][kc * 32 + g * 8]);
          accB[dt] = __builtin_amdgcn_mfma_f32_16x16x32_bf16(pf, vf, accB[dt], 0, 0, 0);
        }
      }
    }
    __builtin_amdgcn_s_setprio(0);
  }

  // ---- epilogues: O = acc / l, in-place over each tile's Q slab ----
  bf16* op = qo + basebh;
  {
    const float linv = 1.f / lA;
    float inv[4];
#pragma unroll
    for (int r = 0; r < 4; ++r) inv[r] = __shfl(linv, g * 4 + r, 64);
#pragma unroll
    for (int dt = 0; dt < 4; ++dt)
#pragma unroll
      for (int r = 0; r < 4; ++r)
        op[(size_t)(qbA + g * 4 + r) * 64 + dt * 16 + l15] =
            __float2bfloat16(accA[dt][r] * inv[r]);
  }
  {
    const float linv = 1.f / lB;
    float inv[4];
#pragma unroll
    for (int r = 0; r < 4; ++r) inv[r] = __shfl(linv, g * 4 + r, 64);
#pragma unroll
    for (int dt = 0; dt < 4; ++dt)
#pragma unroll
      for (int r = 0; r < 4; ++r)
        op[(size_t)(qbB + g * 4 + r) * 64 + dt * 16 + l15] =
            __float2bfloat16(accB[dt][r] * inv[r]);
  }
}

// ---------- Kernel 3: projection via MFMA, 256x128 tile, 16 waves, DEPTH-2 prefetch ----------
// (byte-identical to the 182.09us round-23 passer)
__global__ __launch_bounds__(1024)
void proj_f(const bf16* __restrict__ A, const float* __restrict__ W,
            const float* __restrict__ bias, float* __restrict__ out)
{
  __shared__ __align__(16) bf16 As[2][256][40];
  __shared__ __align__(16) bf16 Bs[2][128][48];
  const int t   = threadIdx.x;
  const int f   = blockIdx.x;               // 0..255
  const int xcd = f & 7, j = f >> 3;        // j 0..31
  const int bm  = xcd * 4 + (j & 3);        // 0..31
  const int bn  = j >> 2;                   // 0..7
  const int gm0 = bm * 256, gn0 = bn * 128;
  const int w    = t >> 6, lane = t & 63;
  const int g    = lane >> 4, l15 = lane & 15;
  const int wr   = w >> 2, wc = w & 3;      // 4x4 wave grid -> wave tile 64x32

  const int am  = t >> 2, akg = t & 3;
  const int bnr = t & 127, kg4 = t >> 7;

  const int gr_l = gm0 + am;
  const int bb_l = gr_l >> 11, s_l = gr_l & 2047;
  const bf16* abase = A + (size_t)bb_l * 2097152 + (size_t)s_l * 64;

  f32x4 acc[4][2];
#pragma unroll
  for (int i = 0; i < 4; i++)
#pragma unroll
    for (int jj = 0; jj < 2; jj++) acc[i][jj] = {0.f, 0.f, 0.f, 0.f};

  const float* wptr = W + (size_t)(kg4 * 4) * 1024 + gn0 + bnr;

  uint4 a0_0, a0_1;
  float wb_0[4], wb_1[4];
  {
    const int c0 = akg * 8;                 // slice 0
    a0_0 = *reinterpret_cast<const uint4*>(abase + (size_t)(c0 >> 6) * 131072 + (c0 & 63));
    const int c1 = 32 + akg * 8;            // slice 32
    a0_1 = *reinterpret_cast<const uint4*>(abase + (size_t)(c1 >> 6) * 131072 + (c1 & 63));
  }
#pragma unroll
  for (int kk = 0; kk < 4; kk++) wb_0[kk] = wptr[kk * 1024];
  wptr += 32 * 1024;
#pragma unroll
  for (int kk = 0; kk < 4; kk++) wb_1[kk] = wptr[kk * 1024];

  for (int kt = 0; kt < 1024; kt += 64) {
    // ---- phase 0: consume slice kt ----
    {
      __align__(8) bf16 bb[4];
#pragma unroll
      for (int i = 0; i < 4; i++) bb[i] = __float2bfloat16(wb_0[i]);
      *reinterpret_cast<uint4*>(&As[0][am][swz8(am, akg)]) = a0_0;
      *reinterpret_cast<uint2*>(&Bs[0][bnr][swz8(bnr, kg4 >> 1) + (kg4 & 1) * 4]) =
          *reinterpret_cast<const uint2*>(bb);
      if (kt + 64 < 1024) {          // issue loads for slice kt+64
        const int c0 = kt + 64 + akg * 8;
        a0_0 = *reinterpret_cast<const uint4*>(abase + (size_t)(c0 >> 6) * 131072 + (c0 & 63));
        wptr += 32 * 1024;
#pragma unroll
        for (int kk = 0; kk < 4; kk++) wb_0[kk] = wptr[kk * 1024];
      }
      __syncthreads();
      bf16x8 af[4], bfr[2];
#pragma unroll
      for (int mt = 0; mt < 4; mt++) {
        const int r_ = wr * 64 + mt * 16 + l15;
        af[mt] = *reinterpret_cast<const bf16x8*>(&As[0][r_][swz8(r_, g)]);
      }
#pragma unroll
      for (int nt = 0; nt < 2; nt++) {
        const int r_ = wc * 32 + nt * 16 + l15;
        bfr[nt] = *reinterpret_cast<const bf16x8*>(&Bs[0][r_][swz8(r_, g)]);
      }
      __builtin_amdgcn_s_setprio(1);
#pragma unroll
      for (int mt = 0; mt < 4; mt++)
#pragma unroll
        for (int nt = 0; nt < 2; nt++)
          acc[mt][nt] = __builtin_amdgcn_mfma_f32_16x16x32_bf16(af[mt], bfr[nt], acc[mt][nt], 0, 0, 0);
      __builtin_amdgcn_s_setprio(0);
    }
    // ---- phase 1: consume slice kt+32 ----
    {
      __align__(8) bf16 bb[4];
#pragma unroll
      for (int i = 0; i < 4; i++) bb[i] = __float2bfloat16(wb_1[i]);
      *reinterpret_cast<uint4*>(&As[1][am][swz8(am, akg)]) = a0_1;
      *reinterpret_cast<uint2*>(&Bs[1][bnr][swz8(bnr, kg4 >> 1) + (kg4 & 1) * 4]) =
          *reinterpret_cast<const uint2*>(bb);
      if (kt + 96 < 1024) {          // issue loads for slice kt+96
        const int c1 = kt + 96 + akg * 8;
        a0_1 = *reinterpret_cast<const uint4*>(abase + (size_t)(c1 >> 6) * 131072 + (c1 & 63));
        wptr += 32 * 1024;
#pragma unroll
        for (int kk = 0; kk < 4; kk++) wb_1[kk] = wptr[kk * 1024];
      }
      __syncthreads();
      bf16x8 af[4], bfr[2];
#pragma unroll
      for (int mt = 0; mt < 4; mt++) {
        const int r_ = wr * 64 + mt * 16 + l15;
        af[mt] = *reinterpret_cast<const bf16x8*>(&As[1][r_][swz8(r_, g)]);
      }
#pragma unroll
      for (int nt = 0; nt < 2; nt++) {
        const int r_ = wc * 32 + nt * 16 + l15;
        bfr[nt] = *reinterpret_cast<const bf16x8*>(&Bs[1][r_][swz8(r_, g)]);
      }
      __builtin_amdgcn_s_setprio(1);
#pragma unroll
      for (int mt = 0; mt < 4; mt++)
#pragma unroll
        for (int nt = 0; nt < 2; nt++)
          acc[mt][nt] = __builtin_amdgcn_mfma_f32_16x16x32_bf16(af[mt], bfr[nt], acc[mt][nt], 0, 0, 0);
      __builtin_amdgcn_s_setprio(0);
    }
  }

#pragma unroll
  for (int nt = 0; nt < 2; nt++) {
    const int gc = gn0 + wc * 32 + nt * 16 + l15;
    const float bvs = bias[gc];
#pragma unroll
    for (int mt = 0; mt < 4; mt++)
#pragma unroll
      for (int r = 0; r < 4; r++) {
        const int gr = gm0 + wr * 64 + mt * 16 + g * 4 + r;
        out[(size_t)gr * 1024 + gc] = acc[mt][nt][r] + bvs;
      }
  }
}

extern "C" void kernel_launch(void* const* d_in, const int* in_sizes, int n_in,
                              void* d_out, int out_size, void* d_ws, size_t ws_size,
                              hipStream_t stream)
{
  const float *x = nullptr, *W_attn = nullptr, *b_attn = nullptr,
              *W_proj = nullptr, *b_proj = nullptr;
  for (int i = 0; i < n_in; i++) {
    switch (in_sizes[i]) {
      case 8388608: x      = (const float*)d_in[i]; break;  // [4,2048,1024]
      case 3145728: W_attn = (const float*)d_in[i]; break;  // [1024,3072]
      case 3072:    b_attn = (const float*)d_in[i]; break;
      case 1048576: W_proj = (const float*)d_in[i]; break;  // [1024,1024]
      case 1024:    b_proj = (const float*)d_in[i]; break;
      default: break;
    }
  }
  if (!x || !W_attn || !b_attn || !W_proj || !b_proj) {
    x = (const float*)d_in[0]; W_attn = (const float*)d_in[1];
    b_attn = (const float*)d_in[2]; W_proj = (const float*)d_in[3];
    b_proj = (const float*)d_in[4];
  }
  float* out = (float*)d_out;        // 8388608 f32 = 32 MiB

  // Memory plan (inputs never written; ws requirement 16 MiB):
  //   Q -> ws[0:16M)  bf16 BHSD, pre-scaled by 0.125*log2e (overwritten by O)
  //   K -> d_out bytes [0:16M)  bf16 BHSD   } dead before proj's f32 writes
  //   V -> d_out bytes [16M:32M) bf16 BHDS  }  (transposed for MFMA PV)
  const size_t NE = 8388608;         // bf16 elements per 16 MiB tensor
  bf16* qb = (bf16*)d_ws;
  bf16* kb = (bf16*)d_out;
  bf16* vb = kb + NE;

  qkv_f <<<dim3(768), 1024, 0, stream>>>(x, W_attn, b_attn, qb, kb, vb);
  attn_f<<<dim3(1024), 256, 0, stream>>>(qb, kb, vb);
  proj_f<<<dim3(256), 1024, 0, stream>>>(qb, W_proj, b_proj, out);
}